// Round 13
// baseline (2492.903 us; speedup 1.0000x reference)
//
#include <hip/hip_runtime.h>
#include <hip/hip_fp16.h>

#define N_NODES 50000
#define HIDDEN  64
#define N_EDGES 1200000

#define BSHIFT 7                       // 128 nodes per bucket
#define BUKSZ  128
#define NBUK   391                     // ceil(50000/128)
#define ABLK   512                     // block-local-sort blocks
#define CH     2344                    // ceil(N_EDGES/ABLK)
#define PAD2   6144                    // csr capacity per bucket (avg ~4030 incl pads)
#define MGRID  2048                    // mega-kernel blocks (8/CU x 256 CU, guaranteed resident)
#define MWAVES (MGRID * 4)             // 8192 waves

typedef unsigned short ushort_t;
typedef _Float16 hf2 __attribute__((ext_vector_type(2)));

__device__ __forceinline__ float bcastf(float v, int k) {
    return __int_as_float(__builtin_amdgcn_readlane(__float_as_int(v), k));
}
__device__ __forceinline__ hf2 u2h(unsigned u) { union { unsigned u; hf2 h; } x; x.u = u; return x.h; }
__device__ __forceinline__ unsigned pkh(float a, float b) {   // 2xf32 -> packed f16
    __half2 h = __float22half2_rn(make_float2(a, b));
    union { __half2 h; unsigned u; } x; x.h = h; return x.u;
}
__device__ __forceinline__ ushort_t f2h(float a) {
    __half h = __float2half_rn(a);
    union { __half h; ushort_t u; } x; x.h = h; return x.u;
}
__device__ __forceinline__ void bfly(float4& a) {      // all lanes end with group-sum
    a.x += __shfl_xor(a.x, 16); a.y += __shfl_xor(a.y, 16);
    a.z += __shfl_xor(a.z, 16); a.w += __shfl_xor(a.w, 16);
    a.x += __shfl_xor(a.x, 32); a.y += __shfl_xor(a.y, 32);
    a.z += __shfl_xor(a.z, 32); a.w += __shfl_xor(a.w, 32);
}

// ---------------- 1) build_a: block-local bucket sort (pure stores) + W pack + bar zero ----------------
__global__ __launch_bounds__(512) void build_a_kernel(const int* __restrict__ ei,
                                                      int* __restrict__ tmp,
                                                      int* __restrict__ starts_m,
                                                      int* __restrict__ counts_m,
                                                      const float* __restrict__ Wn2, const float* __restrict__ Ws2,
                                                      const float* __restrict__ Wn3, const float* __restrict__ Ws3,
                                                      const float* __restrict__ Wn4, const float* __restrict__ Ws4,
                                                      uint4* __restrict__ pw,
                                                      int* __restrict__ bar,
                                                      ushort_t* __restrict__ tbB) {
    __shared__ int hist[NBUK];
    __shared__ int cur[NBUK];
    __shared__ int stage[CH];
    int b = blockIdx.x, tid = threadIdx.x;
    if (b < ABLK) {
        int base = b * CH;
        int cnt = N_EDGES - base; if (cnt > CH) cnt = CH;
        for (int i = tid; i < NBUK; i += 512) hist[i] = 0;
        __syncthreads();
        for (int i = tid; i < cnt; i += 512)
            atomicAdd(&hist[ei[N_EDGES + base + i] >> BSHIFT], 1);
        __syncthreads();
        int v = (tid < NBUK) ? hist[tid] : 0;
#pragma unroll
        for (int o = 1; o < NBUK; o <<= 1) {           // Hillis-Steele inclusive
            __syncthreads();
            int y = (tid >= o && tid < NBUK) ? hist[tid - o] : 0;
            __syncthreads();
            if (tid < NBUK) hist[tid] += y;
        }
        __syncthreads();
        if (tid < NBUK) {
            int excl = hist[tid] - v;
            cur[tid] = excl;
            starts_m[tid * ABLK + b] = base + excl;
            counts_m[tid * ABLK + b] = v;
        }
        __syncthreads();
        for (int i = tid; i < cnt; i += 512) {
            int src = ei[base + i];
            int dst = ei[N_EDGES + base + i];
            int p = atomicAdd(&cur[dst >> BSHIFT], 1);
            stage[p] = src | ((dst & (BUKSZ - 1)) << 16);
        }
        __syncthreads();
        for (int i = tid; i < cnt; i += 512) tmp[base + i] = stage[i];
    } else {
        // pack Wn|Ws (layers 2..4) as f16 k-pairs: pw[layer][kp*16+q] (Wn), +512 (Ws)
        int layer = b - ABLK;
        const float* Wn = (layer == 0) ? Wn2 : (layer == 1) ? Wn3 : Wn4;
        const float* Ws = (layer == 0) ? Ws2 : (layer == 1) ? Ws3 : Ws4;
        int kp = tid >> 4, q = tid & 15;           // tid < 512
        {
            const float4 a = *(const float4*)(Wn + (2 * kp) * 64 + 4 * q);
            const float4 c = *(const float4*)(Wn + (2 * kp + 1) * 64 + 4 * q);
            pw[layer * 1024 + tid] = make_uint4(pkh(a.x, c.x), pkh(a.y, c.y), pkh(a.z, c.z), pkh(a.w, c.w));
        }
        {
            const float4 a = *(const float4*)(Ws + (2 * kp) * 64 + 4 * q);
            const float4 c = *(const float4*)(Ws + (2 * kp + 1) * 64 + 4 * q);
            pw[layer * 1024 + 512 + tid] = make_uint4(pkh(a.x, c.x), pkh(a.y, c.y), pkh(a.z, c.z), pkh(a.w, c.w));
        }
        if (layer == 0) {
            if (tid < 8) bar[tid] = 0;                           // grid-barrier counters
            if (tid < 32) ((unsigned*)(tbB + (size_t)N_NODES * 64))[tid] = 0;  // tbB zero row
        }
    }
}

// ---------------- 2) build_b: per-bucket counting sort (16-aligned, zero-row pads) + gemm1 ----------------
__global__ __launch_bounds__(512) void build_b_kernel(const int* __restrict__ tmp,
                                                      const int* __restrict__ starts_m,
                                                      const int* __restrict__ counts_m,
                                                      int2* __restrict__ row_info,
                                                      ushort_t* __restrict__ csr,
                                                      const float* __restrict__ x,
                                                      const float* __restrict__ Wrel,
                                                      const float* __restrict__ Wroot,
                                                      const float* __restrict__ bias,
                                                      ushort_t* __restrict__ tbf,
                                                      ushort_t* __restrict__ ubf) {
    __shared__ int sl[ABLK];
    __shared__ int cl[ABLK];
    __shared__ int hist[BUKSZ];
    __shared__ int cur[BUKSZ];
    __shared__ ushort_t stage[PAD2];
    int b = blockIdx.x, tid = threadIdx.x;
    if (b < NBUK) {
        sl[tid] = starts_m[b * ABLK + tid];
        cl[tid] = counts_m[b * ABLK + tid];
        if (tid < BUKSZ) hist[tid] = 0;
        __syncthreads();
        {   // thread-per-segment histogram
            int s = sl[tid], c = cl[tid];
            for (int i = 0; i < c; ++i) atomicAdd(&hist[tmp[s + i] >> 16], 1);
        }
        __syncthreads();
        int v = (tid < BUKSZ) ? hist[tid] : 0;
        int vr = (v + 15) & ~15;               // 16-aligned per-node segment (clamp-free agg)
        __syncthreads();
        if (tid < BUKSZ) hist[tid] = vr;
#pragma unroll
        for (int o = 1; o < BUKSZ; o <<= 1) {
            __syncthreads();
            int y = (tid >= o && tid < BUKSZ) ? hist[tid - o] : 0;
            __syncthreads();
            if (tid < BUKSZ) hist[tid] += y;
        }
        __syncthreads();
        int excl = 0;
        if (tid < BUKSZ) {
            excl = hist[tid] - vr;
            cur[tid] = excl;
            int node = (b << BSHIFT) + tid;
            if (node < N_NODES) row_info[node] = make_int2(b * PAD2 + excl, v);
        }
        __syncthreads();
        if (tid < BUKSZ) {                     // pad slots -> zero-row index
            for (int p = v; p < vr; ++p) stage[excl + p] = (ushort_t)N_NODES;
        }
        {   // thread-per-segment placement
            int s = sl[tid], c = cl[tid];
            for (int i = 0; i < c; ++i) {
                int p = tmp[s + i];
                int slot = atomicAdd(&cur[p >> 16], 1);
                stage[slot] = (ushort_t)(p & 0xFFFF);
            }
        }
        __syncthreads();
        int total = hist[BUKSZ - 1];
        for (int i = tid; i < total; i += 512) csr[b * PAD2 + i] = stage[i];
    } else {
        // gemm1: t1 = x@Wrel (f16), u1 = x@Wroot + b1 (f16)
        int lane = tid & 63;
        float wn[64], ws[64];
#pragma unroll
        for (int k = 0; k < 64; ++k) {
            wn[k] = Wrel[k * 64 + lane];
            ws[k] = Wroot[k * 64 + lane];
        }
        float bv = bias[lane];
        int wave = (b - NBUK) * 8 + (tid >> 6);
        int nwaves = (gridDim.x - NBUK) * 8;
        if (wave == 0) tbf[(size_t)N_NODES * 64 + lane] = 0;   // tbA zero row
        for (int i = wave; i < N_NODES; i += nwaves) {
            float hv = x[i * 64 + lane];
            float tacc = 0.f, uacc = bv;
#pragma unroll
            for (int k = 0; k < 64; ++k) {
                float hk = bcastf(hv, k);
                tacc = fmaf(hk, wn[k], tacc);
                uacc = fmaf(hk, ws[k], uacc);
            }
            tbf[(size_t)i * 64 + lane] = f2h(tacc);
            ubf[(size_t)i * 64 + lane] = f2h(uacc);
        }
    }
}

// ---------------- clamp-free f16 gather-aggregate (R12-proven) ----------------
__device__ __forceinline__ float4 agg_core(const ushort_t* __restrict__ tbf,
                                           const ushort_t* __restrict__ csr,
                                           int start, int deg, int g, int q) {
    const ushort_t* cp = csr + start;          // 16-aligned, pads -> zero row
    hf2 l0{0,0}, l1{0,0}, l2{0,0}, l3{0,0};
    hf2 m0{0,0}, m1{0,0}, m2{0,0}, m3{0,0};
    int vr = (deg + 15) & ~15;
    for (int base = 0; base < vr; base += 16) {
        int m = base + 4 * g;
        const uint2 iv = *(const uint2*)(cp + m);
        int s0 = (int)(iv.x & 0xFFFF);
        int s1 = (int)(iv.x >> 16);
        int s2 = (int)(iv.y & 0xFFFF);
        int s3 = (int)(iv.y >> 16);
        const uint2 w0 = *(const uint2*)(tbf + (size_t)s0 * 64 + q * 4);
        const uint2 w1 = *(const uint2*)(tbf + (size_t)s1 * 64 + q * 4);
        const uint2 w2 = *(const uint2*)(tbf + (size_t)s2 * 64 + q * 4);
        const uint2 w3 = *(const uint2*)(tbf + (size_t)s3 * 64 + q * 4);
        l0 += u2h(w0.x); m0 += u2h(w0.y);
        l1 += u2h(w1.x); m1 += u2h(w1.y);
        l2 += u2h(w2.x); m2 += u2h(w2.y);
        l3 += u2h(w3.x); m3 += u2h(w3.y);
    }
    hf2 lo = (l0 + l1) + (l2 + l3);
    hf2 hi = (m0 + m1) + (m2 + m3);
    float4 acc = make_float4((float)lo.x, (float)lo.y, (float)hi.x, (float)hi.y);
    bfly(acc);
    return acc;
}

__device__ __forceinline__ float4 unpack_u(const ushort_t* __restrict__ ubf, int node, int q) {
    const uint2 uv = *(const uint2*)(ubf + (size_t)node * 64 + q * 4);
    hf2 a = u2h(uv.x), b = u2h(uv.y);
    return make_float4((float)a.x, (float)a.y, (float)b.x, (float)b.y);
}

// ---------------- 3) mega: all 4 layers with software grid barriers ----------------
__global__ __launch_bounds__(256, 8) void mega_kernel(ushort_t* __restrict__ tbA,
                                                      ushort_t* __restrict__ ubA,
                                                      ushort_t* __restrict__ tbB,
                                                      ushort_t* __restrict__ ubB,
                                                      const int2* __restrict__ row_info,
                                                      const ushort_t* __restrict__ csr,
                                                      const uint4* __restrict__ pw,
                                                      const float* __restrict__ b2,
                                                      const float* __restrict__ b3,
                                                      const float* __restrict__ b4,
                                                      float* __restrict__ out1,
                                                      float* __restrict__ out2,
                                                      int* __restrict__ bar) {
    __shared__ uint4 wlds[1024];   // f16-pair packed Wn|Ws, 16 KB, linear (0 conflicts)
    __shared__ float blds[64];
    int tid = threadIdx.x;
    int lane = tid & 63, g = lane >> 4, q = lane & 15;
    int w = blockIdx.x * 4 + (tid >> 6);

    const ushort_t* tins[4]  = {tbA, tbB, tbA, tbB};
    const ushort_t* uins[4]  = {ubA, ubB, ubA, ubB};
    ushort_t* touts[3]       = {tbB, tbA, tbB};
    ushort_t* uouts[3]       = {ubB, ubA, ubB};
    const float* biases[3]   = {b2, b3, b4};

#pragma unroll
    for (int p = 0; p < 4; ++p) {
        if (p < 3) {
            const uint4* pwL = pw + p * 1024;
            for (int i = tid; i < 1024; i += 256) wlds[i] = pwL[i];
            if (tid < 64) blds[tid] = biases[p][tid];
        }
        __syncthreads();
        const ushort_t* tin = tins[p];
        const ushort_t* uin = uins[p];
        for (int node = w; node < N_NODES; node += MWAVES) {
            int2 ri = row_info[node];
            float4 acc = agg_core(tin, csr, ri.x, ri.y, g, q);
            float sc = (p == 0) ? 1.f / fmaxf((float)ri.y, 1.f) : 1.f;
            const float4 uv = unpack_u(uin, node, q);
            float4 h;
            h.x = fmaxf(uv.x + acc.x * sc, 0.f);
            h.y = fmaxf(uv.y + acc.y * sc, 0.f);
            h.z = fmaxf(uv.z + acc.z * sc, 0.f);
            h.w = fmaxf(uv.w + acc.w * sc, 0.f);
            if (p == 1 && g == 0)
                *(float4*)(out1 + (size_t)node * 64 + q * 4) = h;
            if (p == 3) {
                if (g == 0)
                    *(float4*)(out2 + (size_t)node * 64 + q * 4) = h;
                continue;
            }
            // f16 dot2 gemm: lane q holds kp=2q (h.x,h.y), kp=2q+1 (h.z,h.w)
            int hp_lo = (int)pkh(h.x, h.y);
            int hp_hi = (int)pkh(h.z, h.w);
            float4 tp{0,0,0,0}, up{0,0,0,0};
#pragma unroll
            for (int jp = 0; jp < 8; ++jp) {
                int kp = 8 * g + jp;
                const uint4 wvn = wlds[kp * 16 + q];
                const uint4 wvs = wlds[512 + kp * 16 + q];
                int srcl = 4 * g + (jp >> 1);
                unsigned hu = (unsigned)__shfl((jp & 1) ? hp_hi : hp_lo, srcl);
                hf2 hh = u2h(hu);
                tp.x = __builtin_amdgcn_fdot2(hh, u2h(wvn.x), tp.x, false);
                tp.y = __builtin_amdgcn_fdot2(hh, u2h(wvn.y), tp.y, false);
                tp.z = __builtin_amdgcn_fdot2(hh, u2h(wvn.z), tp.z, false);
                tp.w = __builtin_amdgcn_fdot2(hh, u2h(wvn.w), tp.w, false);
                up.x = __builtin_amdgcn_fdot2(hh, u2h(wvs.x), up.x, false);
                up.y = __builtin_amdgcn_fdot2(hh, u2h(wvs.y), up.y, false);
                up.z = __builtin_amdgcn_fdot2(hh, u2h(wvs.z), up.z, false);
                up.w = __builtin_amdgcn_fdot2(hh, u2h(wvs.w), up.w, false);
            }
            bfly(tp); bfly(up);
            if (g == 0) {
                const float4 bv = *(const float4*)&blds[q * 4];
                uint2 upk, tpk;
                upk.x = pkh(up.x + bv.x, up.y + bv.y);
                upk.y = pkh(up.z + bv.z, up.w + bv.w);
                tpk.x = pkh(tp.x, tp.y);
                tpk.y = pkh(tp.z, tp.w);
                *(uint2*)(uouts[p] + (size_t)node * 64 + q * 4) = upk;
                *(uint2*)(touts[p] + (size_t)node * 64 + q * 4) = tpk;
            }
        }
        if (p < 3) {
            // software grid barrier #p (all MGRID blocks guaranteed co-resident)
            __threadfence();
            __syncthreads();
            if (tid == 0) {
                __hip_atomic_fetch_add(&bar[p], 1, __ATOMIC_ACQ_REL, __HIP_MEMORY_SCOPE_AGENT);
                while (__hip_atomic_load(&bar[p], __ATOMIC_ACQUIRE, __HIP_MEMORY_SCOPE_AGENT) < MGRID)
                    __builtin_amdgcn_s_sleep(2);
            }
            __syncthreads();
        }
    }
}

// ---------------- launch: 3 dispatches ----------------
extern "C" void kernel_launch(void* const* d_in, const int* in_sizes, int n_in,
                              void* d_out, int out_size, void* d_ws, size_t ws_size,
                              hipStream_t stream) {
    const float* x      = (const float*)d_in[0];
    const int*   ei     = (const int*)d_in[1];
    const float* Wrel1  = (const float*)d_in[2];
    const float* Wroot1 = (const float*)d_in[3];
    const float* b1     = (const float*)d_in[4];
    const float* Wself2 = (const float*)d_in[5];
    const float* Wnbr2  = (const float*)d_in[6];
    const float* b2     = (const float*)d_in[7];
    const float* Wself3 = (const float*)d_in[8];
    const float* Wnbr3  = (const float*)d_in[9];
    const float* b3     = (const float*)d_in[10];
    const float* Wself4 = (const float*)d_in[11];
    const float* Wnbr4  = (const float*)d_in[12];
    const float* b4     = (const float*)d_in[13];

    const int N = N_NODES;

    auto align = [](size_t o) { return (o + 255) & ~(size_t)255; };
    char* base = (char*)d_ws;
    size_t off = 0;
    int*  tmp      = (int*)(base + off);  off = align(off + (size_t)ABLK * CH * 4);
    int*  starts_m = (int*)(base + off);  off = align(off + (size_t)NBUK * ABLK * 4);
    int*  counts_m = (int*)(base + off);  off = align(off + (size_t)NBUK * ABLK * 4);
    int2* row_info = (int2*)(base + off); off = align(off + (size_t)N * 8);
    ushort_t* csr  = (ushort_t*)(base + off); off = align(off + (size_t)NBUK * PAD2 * 2 + 1024);
    uint4* pw      = (uint4*)(base + off);    off = align(off + (size_t)3 * 1024 * 16);
    ushort_t* tbA  = (ushort_t*)(base + off); off = align(off + (size_t)(N + 1) * 64 * 2);
    ushort_t* tbB  = (ushort_t*)(base + off); off = align(off + (size_t)(N + 1) * 64 * 2);
    ushort_t* ubA  = (ushort_t*)(base + off); off = align(off + (size_t)N * 64 * 2);
    ushort_t* ubB  = (ushort_t*)(base + off); off = align(off + (size_t)N * 64 * 2);
    int* bar       = (int*)(base + off);      off = align(off + 256);

    float* out1 = (float*)d_out;
    float* out2 = (float*)d_out + (size_t)N * 64;

    // 1) block-local bucket sort + W pack + bar zero + tbB zero row
    build_a_kernel<<<ABLK + 3, 512, 0, stream>>>(ei, tmp, starts_m, counts_m,
                                                 Wnbr2, Wself2, Wnbr3, Wself3, Wnbr4, Wself4,
                                                 pw, bar, tbB);
    // 2) per-bucket counting sort (16-aligned, zero-row pads) || gemm1 -> t1(tbA), u1(ubA)
    build_b_kernel<<<NBUK + 1024, 512, 0, stream>>>(tmp, starts_m, counts_m, row_info, csr,
                                                    x, Wrel1, Wroot1, b1, tbA, ubA);
    // 3) mega: L1..L4 with software grid barriers
    mega_kernel<<<MGRID, 256, 0, stream>>>(tbA, ubA, tbB, ubB, row_info, csr, pw,
                                           b2, b3, b4, out1, out2, bar);
}